// Round 8
// baseline (190.624 us; speedup 1.0000x reference)
//
#include <hip/hip_runtime.h>

// Problem constants
#define BATCH 2
#define NSEQ 2304       // 48*48
#define DIM 768
#define HEADS 12
#define HD 64
#define M_TOK (BATCH * NSEQ)   // 4608
#define LDSP 72                // padded LDS row stride (bf16 elems)
#define KP 72                  // attn LDS stride (elems) for K (bf16) and V^T (f16)
#define BH (BATCH * HEADS)     // 24
#define KT_HALF (NSEQ / 64 / 2) // 18 key-tiles per half

typedef __attribute__((ext_vector_type(8))) short bf16x8;
typedef __attribute__((ext_vector_type(8))) short short8v;
typedef __attribute__((ext_vector_type(4))) float f32x4;
typedef __fp16 fp16x2 __attribute__((ext_vector_type(2)));
typedef _Float16 half4 __attribute__((ext_vector_type(4)));
typedef _Float16 half8 __attribute__((ext_vector_type(8)));

// softmax scale folded with log2(e): exp(x) = exp2(x * log2e)
#define QSCALE (0.125f * 1.44269504088896f)
#define LOG2_100_D16 0.41524101186092029f   // log2(100)/16

__device__ __forceinline__ short f2bf(float f) {
    union { float f; unsigned u; } v; v.f = f;
    unsigned r = v.u + 0x7fffu + ((v.u >> 16) & 1u);
    return (short)(r >> 16);
}

// ---------------- merged fp32 -> bf16 conversion for x, w_qkv, w_proj ----------------
#define CN1 (M_TOK * DIM / 4)        // 884736
#define CN2 (3 * DIM * DIM / 4)      // 442368
#define CN3 (DIM * DIM / 4)          // 147456
__global__ void cvt_all_kernel(const float* __restrict__ x, const float* __restrict__ wq,
                               const float* __restrict__ wp,
                               short* __restrict__ xb, short* __restrict__ wqb,
                               short* __restrict__ wpb) {
    int i = blockIdx.x * 256 + threadIdx.x;
    const float* src; short* dst; int j;
    if (i < CN1)              { src = x;  dst = xb;  j = i; }
    else if (i < CN1 + CN2)   { src = wq; dst = wqb; j = i - CN1; }
    else                      { src = wp; dst = wpb; j = i - CN1 - CN2; }
    float4 v = reinterpret_cast<const float4*>(src)[j];
    short4 o;
    o.x = f2bf(v.x); o.y = f2bf(v.y); o.z = f2bf(v.z); o.w = f2bf(v.w);
    reinterpret_cast<short4*>(dst)[j] = o;
}

// ---------------- qkv GEMM: 128x128 tile, double-buffered LDS, 1 barrier/iter ----------------
// fused bias + RoPE + QSCALE; q,k -> [b,h,tok,d] bf16 ; v -> [b,h,d,tok] f16
__global__ __launch_bounds__(256) void gemm_qkv_kernel(
    const short* __restrict__ A,    // xb [4608,768]
    const short* __restrict__ Bt,   // wqkvb [2304,768]
    const float* __restrict__ bias, // [2304]
    short* __restrict__ qb, short* __restrict__ kbuf, _Float16* __restrict__ vtb)
{
    __shared__ __align__(16) short At[2][128 * LDSP];
    __shared__ __align__(16) short Bl[2][128 * LDSP];
    const int m0 = blockIdx.x * 128, n0 = blockIdx.y * 128;
    const int tid = threadIdx.x, lane = tid & 63, wave = tid >> 6;
    const int quad = lane >> 4, l16 = lane & 15;
    const int wm = (wave >> 1) * 64, wn = (wave & 1) * 64;
    const int r = tid >> 1, c0 = (tid & 1) * 32;
    f32x4 acc[4][4] = {};

    // prologue: stage k-tile 0 into buffer 0
    {
        const uint4* ga = reinterpret_cast<const uint4*>(&A[(size_t)(m0 + r) * DIM + c0]);
        const uint4* gb = reinterpret_cast<const uint4*>(&Bt[(size_t)(n0 + r) * DIM + c0]);
        uint4 a0 = ga[0], a1 = ga[1], a2 = ga[2], a3 = ga[3];
        uint4 b0 = gb[0], b1 = gb[1], b2 = gb[2], b3 = gb[3];
        uint4* sa = reinterpret_cast<uint4*>(&At[0][r * LDSP + c0]);
        uint4* sb = reinterpret_cast<uint4*>(&Bl[0][r * LDSP + c0]);
        sa[0] = a0; sa[1] = a1; sa[2] = a2; sa[3] = a3;
        sb[0] = b0; sb[1] = b1; sb[2] = b2; sb[3] = b3;
    }

    int cur = 0;
    for (int k0 = 0; k0 < DIM; k0 += 64) {
        __syncthreads();   // buf[cur] visible; everyone done reading buf[cur^1]
        uint4 a0, a1, a2, a3, b0, b1, b2, b3;
        const bool pre = (k0 + 64 < DIM);
        if (pre) {   // issue AFTER barrier: latency hides under this iter's MFMA
            const uint4* ga = reinterpret_cast<const uint4*>(&A[(size_t)(m0 + r) * DIM + k0 + 64 + c0]);
            const uint4* gb = reinterpret_cast<const uint4*>(&Bt[(size_t)(n0 + r) * DIM + k0 + 64 + c0]);
            a0 = ga[0]; a1 = ga[1]; a2 = ga[2]; a3 = ga[3];
            b0 = gb[0]; b1 = gb[1]; b2 = gb[2]; b3 = gb[3];
        }
#pragma unroll
        for (int ks = 0; ks < 2; ++ks) {
            bf16x8 af[4], bf[4];
#pragma unroll
            for (int mt = 0; mt < 4; ++mt)
                af[mt] = *reinterpret_cast<const bf16x8*>(&At[cur][(wm + mt * 16 + l16) * LDSP + ks * 32 + quad * 8]);
#pragma unroll
            for (int nt = 0; nt < 4; ++nt)
                bf[nt] = *reinterpret_cast<const bf16x8*>(&Bl[cur][(wn + nt * 16 + l16) * LDSP + ks * 32 + quad * 8]);
#pragma unroll
            for (int mt = 0; mt < 4; ++mt)
#pragma unroll
                for (int nt = 0; nt < 4; ++nt)
                    acc[mt][nt] = __builtin_amdgcn_mfma_f32_16x16x32_bf16(af[mt], bf[nt], acc[mt][nt], 0, 0, 0);
        }
        if (pre) {
            uint4* sa = reinterpret_cast<uint4*>(&At[cur ^ 1][r * LDSP + c0]);
            uint4* sb = reinterpret_cast<uint4*>(&Bl[cur ^ 1][r * LDSP + c0]);
            sa[0] = a0; sa[1] = a1; sa[2] = a2; sa[3] = a3;
            sb[0] = b0; sb[1] = b1; sb[2] = b2; sb[3] = b3;
        }
        cur ^= 1;
    }

    const int which = (n0 + wn) / DIM;          // 0=q 1=k 2=v (wave-uniform)
    const int head = ((n0 + wn) % DIM) / HD;
    const int b = m0 / NSEQ;
    const int tokb = m0 % NSEQ + wm;
    if (which == 2) {
#pragma unroll
        for (int mt = 0; mt < 4; ++mt)
#pragma unroll
            for (int nt = 0; nt < 4; ++nt) {
                const int n = n0 + wn + nt * 16 + l16;
                const int d = nt * 16 + l16;
                const float bi = bias[n];
                const int tok0 = tokb + mt * 16 + quad * 4;
                half4 hv;
                hv.x = (_Float16)(acc[mt][nt][0] + bi);
                hv.y = (_Float16)(acc[mt][nt][1] + bi);
                hv.z = (_Float16)(acc[mt][nt][2] + bi);
                hv.w = (_Float16)(acc[mt][nt][3] + bi);
                *reinterpret_cast<half4*>(&vtb[((size_t)(b * HEADS + head) * HD + d) * NSEQ + tok0]) = hv;
            }
    } else {
        // fused RoPE: pairs (d, d+32) = (nt, nt+2); pi = l16
        short* dst = (which == 0) ? qb : kbuf;
        const float qs = (which == 0) ? QSCALE : 1.0f;
        float bi[4];
#pragma unroll
        for (int nt = 0; nt < 4; ++nt) bi[nt] = bias[n0 + wn + nt * 16 + l16];
        const float invp = __builtin_amdgcn_exp2f(-(float)l16 * LOG2_100_D16); // 100^(-l16/16)
#pragma unroll
        for (int mt = 0; mt < 4; ++mt) {
#pragma unroll
            for (int rg = 0; rg < 4; ++rg) {
                const int tok = tokb + mt * 16 + quad * 4 + rg;
                const int yy = tok / 48, xx = tok - yy * 48;
                const float ry = (2.0f * (yy + 0.5f) * (1.0f / 48.0f) - 1.0f) * invp; // revolutions
                const float rx = (2.0f * (xx + 0.5f) * (1.0f / 48.0f) - 1.0f) * invp;
                const float sy = __builtin_amdgcn_sinf(ry), cy = __builtin_amdgcn_cosf(ry);
                const float sx = __builtin_amdgcn_sinf(rx), cx = __builtin_amdgcn_cosf(rx);
                const float a0 = acc[mt][0][rg] + bi[0];
                const float a1 = acc[mt][1][rg] + bi[1];
                const float a2 = acc[mt][2][rg] + bi[2];
                const float a3 = acc[mt][3][rg] + bi[3];
                short* rp = &dst[((size_t)(b * HEADS + head) * NSEQ + tok) * HD];
                rp[l16]      = f2bf((a0 * cy - a2 * sy) * qs);
                rp[32 + l16] = f2bf((a2 * cy + a0 * sy) * qs);
                rp[16 + l16] = f2bf((a1 * cx - a3 * sx) * qs);
                rp[48 + l16] = f2bf((a3 * cx + a1 * sx) * qs);
            }
        }
    }
}

// ---------------- flash attention, key-split partials, XCD-swizzled grid ----------------
// 1D grid of 864 blocks. Decode so all 18 q-tile blocks sharing one (kh,bh) K/V slab
// land on the same XCD (wg & 7 under round-robin dispatch): per-XCD L2 working set
// = 6 slabs x 294 KB = 1.8 MB < 4 MB L2 -> K/V prefetches become L2 hits.
__global__ __launch_bounds__(256) void attn_kernel(
    const short* __restrict__ qb, const short* __restrict__ kb,
    const _Float16* __restrict__ vtb, _Float16* __restrict__ opart,
    float* __restrict__ lpart)
{
    __shared__ __align__(16) short    Kt[2][64 * KP];   // [key][d]   bf16
    __shared__ __align__(16) _Float16 Vt[2][64 * KP];   // [d][tok]   f16
    const int wg = blockIdx.x;
    const int xcd = wg & 7;
    const int slot = wg >> 3;            // 0..107
    const int slab = xcd * 6 + slot / 18; // 0..47
    const int qt = slot % 18;
    const int kh = slab & 1;
    const int bh = slab >> 1;
    const int tid = threadIdx.x, lane = tid & 63, wave = tid >> 6;
    const int quad = lane >> 4, l16 = lane & 15;
    const int qrow0 = qt * 128 + wave * 32;
    const short* qbase = qb + (size_t)bh * NSEQ * HD;
    const short* kbase = kb + (size_t)bh * NSEQ * HD;
    const _Float16* vbase = vtb + (size_t)bh * HD * NSEQ;

    bf16x8 qf[2][2];
#pragma unroll
    for (int mt = 0; mt < 2; ++mt)
#pragma unroll
        for (int ks = 0; ks < 2; ++ks)
            qf[mt][ks] = *reinterpret_cast<const bf16x8*>(
                &qbase[(size_t)(qrow0 + mt * 16 + l16) * HD + ks * 32 + quad * 8]);

    half4 ones;
    ones.x = ones.y = ones.z = ones.w = (_Float16)1.0f;

    f32x4 oacc[2][4] = {};
    f32x4 lacc[2] = {};

    const int r = tid >> 2, cq = (tid & 3) * 16;
    const int t0 = kh * KT_HALF;
    // incrementally-bumped global pointers (trim per-tile 64-bit address VALU)
    const short* kp = kbase + (size_t)(t0 * 64 + r) * HD + cq;
    const _Float16* vp = vbase + (size_t)r * NSEQ + t0 * 64 + cq;
    // prologue: stage first tile into buffer 0
    {
        const uint4* gk = reinterpret_cast<const uint4*>(kp);
        uint4 k0 = gk[0], k1 = gk[1];
        const uint4* gv = reinterpret_cast<const uint4*>(vp);
        uint4 v0 = gv[0], v1 = gv[1];
        uint4* sk = reinterpret_cast<uint4*>(&Kt[0][r * KP + cq]);
        sk[0] = k0; sk[1] = k1;
        uint4* sv = reinterpret_cast<uint4*>(&Vt[0][r * KP + cq]);
        sv[0] = v0; sv[1] = v1;
        kp += 64 * HD;
        vp += 64;
    }

    int cur = 0;
    for (int kt = 0; kt < KT_HALF; ++kt) {
        __syncthreads();   // buf[cur] visible; readers of buf[cur^1] done
        uint4 k0, k1, v0, v1;
        const bool pre = (kt + 1 < KT_HALF);
        if (pre) {   // issue AFTER barrier
            const uint4* gk = reinterpret_cast<const uint4*>(kp);
            k0 = gk[0]; k1 = gk[1];
            const uint4* gv = reinterpret_cast<const uint4*>(vp);
            v0 = gv[0]; v1 = gv[1];
            kp += 64 * HD;
            vp += 64;
        }

        // S^T = K Q^T : C rows = keys (quad*4+rg), cols = q-rows (l16)
        f32x4 sacc[4][2] = {};
#pragma unroll
        for (int ks = 0; ks < 2; ++ks) {
#pragma unroll
            for (int nt = 0; nt < 4; ++nt) {
                bf16x8 kf = *reinterpret_cast<const bf16x8*>(
                    &Kt[cur][(nt * 16 + l16) * KP + ks * 32 + quad * 8]);
#pragma unroll
                for (int mt = 0; mt < 2; ++mt)
                    sacc[nt][mt] = __builtin_amdgcn_mfma_f32_16x16x32_bf16(
                        kf, qf[mt][ks], sacc[nt][mt], 0, 0, 0);
            }
        }

        // P = exp2(S^T): packs directly into f16 A-fragments (A[m=l16][k=quad*4+j])
        half4 pf[2][4];
#pragma unroll
        for (int mt = 0; mt < 2; ++mt)
#pragma unroll
            for (int nt = 0; nt < 4; ++nt) {
                fp16x2 lo = __builtin_amdgcn_cvt_pkrtz(
                    __builtin_amdgcn_exp2f(sacc[nt][mt][0]),
                    __builtin_amdgcn_exp2f(sacc[nt][mt][1]));
                fp16x2 hi = __builtin_amdgcn_cvt_pkrtz(
                    __builtin_amdgcn_exp2f(sacc[nt][mt][2]),
                    __builtin_amdgcn_exp2f(sacc[nt][mt][3]));
                half4 p;
                p.x = (_Float16)lo.x; p.y = (_Float16)lo.y;
                p.z = (_Float16)hi.x; p.w = (_Float16)hi.y;
                pf[mt][nt] = p;
            }

        // l += P * ones (row sums in C-layout, matches oacc rows)
#pragma unroll
        for (int mt = 0; mt < 2; ++mt)
#pragma unroll
            for (int nt = 0; nt < 4; ++nt)
                lacc[mt] = __builtin_amdgcn_mfma_f32_16x16x16f16(
                    pf[mt][nt], ones, lacc[mt], 0, 0, 0);

        // O += P V
#pragma unroll
        for (int nt = 0; nt < 4; ++nt)
#pragma unroll
            for (int dt = 0; dt < 4; ++dt) {
                half4 vf = *reinterpret_cast<const half4*>(
                    &Vt[cur][(dt * 16 + l16) * KP + nt * 16 + quad * 4]);
#pragma unroll
                for (int mt = 0; mt < 2; ++mt)
                    oacc[mt][dt] = __builtin_amdgcn_mfma_f32_16x16x16f16(
                        pf[mt][nt], vf, oacc[mt][dt], 0, 0, 0);
            }

        if (pre) {   // vmcnt wait lands here, after the tile's compute
            uint4* sk = reinterpret_cast<uint4*>(&Kt[cur ^ 1][r * KP + cq]);
            sk[0] = k0; sk[1] = k1;
            uint4* sv = reinterpret_cast<uint4*>(&Vt[cur ^ 1][r * KP + cq]);
            sv[0] = v0; sv[1] = v1;
        }
        cur ^= 1;
    }

    // store UNNORMALIZED partials
    _Float16* ob2 = opart + (size_t)(kh * BH + bh) * NSEQ * HD;
    float* lp2 = lpart + (size_t)(kh * BH + bh) * NSEQ;
#pragma unroll
    for (int mt = 0; mt < 2; ++mt) {
#pragma unroll
        for (int dt = 0; dt < 4; ++dt)
#pragma unroll
            for (int rg = 0; rg < 4; ++rg) {
                int row = qrow0 + mt * 16 + quad * 4 + rg;
                ob2[(size_t)row * HD + dt * 16 + l16] = (_Float16)oacc[mt][dt][rg];
            }
        if (l16 == 0) {
#pragma unroll
            for (int rg = 0; rg < 4; ++rg)
                lp2[qrow0 + mt * 16 + quad * 4 + rg] = lacc[mt][rg];
        }
    }
}

// ---------------- proj GEMM with fused softmax-combine ----------------
__global__ __launch_bounds__(256) void gemm_proj_kernel(
    const _Float16* __restrict__ op,  // [2][bh][row][d] f16 partials
    const float* __restrict__ lp,     // [2][bh][row] f32 partials
    const short* __restrict__ Bt,     // wprojb [768,768]
    const float* __restrict__ bias,   // [768]
    float* __restrict__ out)
{
    __shared__ __align__(16) short At[64 * LDSP];
    __shared__ __align__(16) short Bl[64 * LDSP];
    const int m0 = blockIdx.x * 64, n0 = blockIdx.y * 64;
    const int tid = threadIdx.x, lane = tid & 63, wave = tid >> 6;
    const int quad = lane >> 4, l16 = lane & 15;
    const int wm = (wave >> 1) * 32, wn = (wave & 1) * 32;
    const int r = tid >> 2, cs = (tid & 3) * 16;
    const int b = m0 / NSEQ;
    const int tok = m0 % NSEQ + r;
    f32x4 acc[2][2] = {};

    for (int k0 = 0; k0 < DIM; k0 += 64) {
        // fused combine: this k-tile is head h
        const int h = k0 >> 6;
        const size_t pb = (size_t)(b * HEADS + h) * NSEQ + tok;
        const float l0 = lp[pb], l1 = lp[(size_t)BH * NSEQ + pb];
        const float inv = __builtin_amdgcn_rcpf(l0 + l1);
        const half8* o0 = reinterpret_cast<const half8*>(&op[pb * HD + cs]);
        const half8* o1 = reinterpret_cast<const half8*>(&op[(size_t)BH * NSEQ * HD + pb * HD + cs]);
        half8 p0 = o0[0], p1 = o0[1], q0 = o1[0], q1 = o1[1];
        const uint4* gb = reinterpret_cast<const uint4*>(&Bt[(size_t)(n0 + r) * DIM + k0 + cs]);
        uint4 bw0 = gb[0], bw1 = gb[1];
        short8v s0, s1;
#pragma unroll
        for (int j = 0; j < 8; ++j) {
            s0[j] = f2bf(((float)p0[j] + (float)q0[j]) * inv);
            s1[j] = f2bf(((float)p1[j] + (float)q1[j]) * inv);
        }
        *reinterpret_cast<short8v*>(&At[r * LDSP + cs]) = s0;
        *reinterpret_cast<short8v*>(&At[r * LDSP + cs + 8]) = s1;
        uint4* sb = reinterpret_cast<uint4*>(&Bl[r * LDSP + cs]);
        sb[0] = bw0; sb[1] = bw1;
        __syncthreads();
#pragma unroll
        for (int ks = 0; ks < 2; ++ks) {
            bf16x8 af[2], bf[2];
#pragma unroll
            for (int mt = 0; mt < 2; ++mt)
                af[mt] = *reinterpret_cast<const bf16x8*>(&At[(wm + mt * 16 + l16) * LDSP + ks * 32 + quad * 8]);
#pragma unroll
            for (int nt = 0; nt < 2; ++nt)
                bf[nt] = *reinterpret_cast<const bf16x8*>(&Bl[(wn + nt * 16 + l16) * LDSP + ks * 32 + quad * 8]);
#pragma unroll
            for (int mt = 0; mt < 2; ++mt)
#pragma unroll
                for (int nt = 0; nt < 2; ++nt)
                    acc[mt][nt] = __builtin_amdgcn_mfma_f32_16x16x32_bf16(af[mt], bf[nt], acc[mt][nt], 0, 0, 0);
        }
        __syncthreads();
    }

#pragma unroll
    for (int mt = 0; mt < 2; ++mt)
#pragma unroll
        for (int nt = 0; nt < 2; ++nt) {
            const int n = n0 + wn + nt * 16 + l16;
            const float bi = bias[n];
#pragma unroll
            for (int rg = 0; rg < 4; ++rg) {
                const int m = m0 + wm + mt * 16 + quad * 4 + rg;
                out[(size_t)m * DIM + n] = acc[mt][nt][rg] + bi;
            }
        }
}

extern "C" void kernel_launch(void* const* d_in, const int* in_sizes, int n_in,
                              void* d_out, int out_size, void* d_ws, size_t ws_size,
                              hipStream_t stream) {
    const float* x      = (const float*)d_in[0];
    const float* w_qkv  = (const float*)d_in[1];
    const float* b_qkv  = (const float*)d_in[2];
    const float* w_proj = (const float*)d_in[3];
    const float* b_proj = (const float*)d_in[4];
    float* out = (float*)d_out;

    short* xb     = (short*)d_ws;                         // 4608*768
    short* wqkvb  = xb + (size_t)M_TOK * DIM;             // 2304*768
    short* wprojb = wqkvb + (size_t)3 * DIM * DIM;        // 768*768
    short* qb     = wprojb + (size_t)DIM * DIM;           // 24*2304*64 bf16
    short* kb     = qb + (size_t)BH * NSEQ * HD;
    short* vtb    = kb + (size_t)BH * NSEQ * HD;          // f16 [bh,d,tok]
    short* opart  = vtb + (size_t)BH * NSEQ * HD;         // f16 [2,bh,row,d]
    float* lpart  = (float*)(opart + (size_t)2 * BH * NSEQ * HD); // f32 [2,bh,row]

    // merged converts (1 kernel)
    cvt_all_kernel<<<(CN1 + CN2 + CN3) / 256, 256, 0, stream>>>(
        x, w_qkv, w_proj, xb, wqkvb, wprojb);

    // qkv GEMM + bias + RoPE + QSCALE + scatter (double-buffered)
    dim3 g1(M_TOK / 128, 3 * DIM / 128);
    gemm_qkv_kernel<<<g1, 256, 0, stream>>>(xb, wqkvb, b_qkv, qb, kb, (_Float16*)vtb);

    // attention partials (key-split x2), XCD-swizzled 1D grid
    attn_kernel<<<dim3(18 * 2 * BH), 256, 0, stream>>>(qb, kb, (const _Float16*)vtb,
                                                       (_Float16*)opart, lpart);

    // proj GEMM with fused combine+normalize
    dim3 g3(M_TOK / 64, DIM / 64);
    gemm_proj_kernel<<<g3, 256, 0, stream>>>((const _Float16*)opart, lpart,
                                             wprojb, b_proj, out);
}

// Round 9
// 173.394 us; speedup vs baseline: 1.0994x; 1.0994x over previous
//
#include <hip/hip_runtime.h>

// Problem constants
#define BATCH 2
#define NSEQ 2304       // 48*48
#define DIM 768
#define HEADS 12
#define HD 64
#define M_TOK (BATCH * NSEQ)   // 4608
#define LDSP 72                // padded LDS row stride (bf16 elems)
#define KP 72                  // attn LDS stride (elems) for K (bf16) and V^T (f16)
#define BH (BATCH * HEADS)     // 24
#define KT_HALF (NSEQ / 64 / 2) // 18 key-tiles per half

typedef __attribute__((ext_vector_type(8))) short bf16x8;
typedef __attribute__((ext_vector_type(8))) short short8v;
typedef __attribute__((ext_vector_type(4))) float f32x4;
typedef __fp16 fp16x2 __attribute__((ext_vector_type(2)));
typedef _Float16 half4 __attribute__((ext_vector_type(4)));
typedef _Float16 half8 __attribute__((ext_vector_type(8)));

// softmax scale folded with log2(e): exp(x) = exp2(x * log2e)
#define QSCALE (0.125f * 1.44269504088896f)
#define LOG2_100_D16 0.41524101186092029f   // log2(100)/16

__device__ __forceinline__ short f2bf(float f) {
    union { float f; unsigned u; } v; v.f = f;
    unsigned r = v.u + 0x7fffu + ((v.u >> 16) & 1u);
    return (short)(r >> 16);
}

// ---------------- merged fp32 -> bf16 conversion for x, w_qkv, w_proj ----------------
#define CN1 (M_TOK * DIM / 4)        // 884736
#define CN2 (3 * DIM * DIM / 4)      // 442368
#define CN3 (DIM * DIM / 4)          // 147456
__global__ void cvt_all_kernel(const float* __restrict__ x, const float* __restrict__ wq,
                               const float* __restrict__ wp,
                               short* __restrict__ xb, short* __restrict__ wqb,
                               short* __restrict__ wpb) {
    int i = blockIdx.x * 256 + threadIdx.x;
    const float* src; short* dst; int j;
    if (i < CN1)              { src = x;  dst = xb;  j = i; }
    else if (i < CN1 + CN2)   { src = wq; dst = wqb; j = i - CN1; }
    else                      { src = wp; dst = wpb; j = i - CN1 - CN2; }
    float4 v = reinterpret_cast<const float4*>(src)[j];
    short4 o;
    o.x = f2bf(v.x); o.y = f2bf(v.y); o.z = f2bf(v.z); o.w = f2bf(v.w);
    reinterpret_cast<short4*>(dst)[j] = o;
}

// ---------------- qkv GEMM: 128x128 tile, double-buffered LDS, 1 barrier/iter ----------------
// fused bias + RoPE + QSCALE; q,k -> [b,h,tok,d] bf16 ; v -> [b,h,d,tok] f16
__global__ __launch_bounds__(256) void gemm_qkv_kernel(
    const short* __restrict__ A,    // xb [4608,768]
    const short* __restrict__ Bt,   // wqkvb [2304,768]
    const float* __restrict__ bias, // [2304]
    short* __restrict__ qb, short* __restrict__ kbuf, _Float16* __restrict__ vtb)
{
    __shared__ __align__(16) short At[2][128 * LDSP];
    __shared__ __align__(16) short Bl[2][128 * LDSP];
    const int m0 = blockIdx.x * 128, n0 = blockIdx.y * 128;
    const int tid = threadIdx.x, lane = tid & 63, wave = tid >> 6;
    const int quad = lane >> 4, l16 = lane & 15;
    const int wm = (wave >> 1) * 64, wn = (wave & 1) * 64;
    const int r = tid >> 1, c0 = (tid & 1) * 32;
    f32x4 acc[4][4] = {};

    // prologue: stage k-tile 0 into buffer 0
    {
        const uint4* ga = reinterpret_cast<const uint4*>(&A[(size_t)(m0 + r) * DIM + c0]);
        const uint4* gb = reinterpret_cast<const uint4*>(&Bt[(size_t)(n0 + r) * DIM + c0]);
        uint4 a0 = ga[0], a1 = ga[1], a2 = ga[2], a3 = ga[3];
        uint4 b0 = gb[0], b1 = gb[1], b2 = gb[2], b3 = gb[3];
        uint4* sa = reinterpret_cast<uint4*>(&At[0][r * LDSP + c0]);
        uint4* sb = reinterpret_cast<uint4*>(&Bl[0][r * LDSP + c0]);
        sa[0] = a0; sa[1] = a1; sa[2] = a2; sa[3] = a3;
        sb[0] = b0; sb[1] = b1; sb[2] = b2; sb[3] = b3;
    }

    int cur = 0;
    for (int k0 = 0; k0 < DIM; k0 += 64) {
        __syncthreads();   // buf[cur] visible; everyone done reading buf[cur^1]
        uint4 a0, a1, a2, a3, b0, b1, b2, b3;
        const bool pre = (k0 + 64 < DIM);
        if (pre) {   // issue AFTER barrier: latency hides under this iter's MFMA
            const uint4* ga = reinterpret_cast<const uint4*>(&A[(size_t)(m0 + r) * DIM + k0 + 64 + c0]);
            const uint4* gb = reinterpret_cast<const uint4*>(&Bt[(size_t)(n0 + r) * DIM + k0 + 64 + c0]);
            a0 = ga[0]; a1 = ga[1]; a2 = ga[2]; a3 = ga[3];
            b0 = gb[0]; b1 = gb[1]; b2 = gb[2]; b3 = gb[3];
        }
#pragma unroll
        for (int ks = 0; ks < 2; ++ks) {
            bf16x8 af[4], bf[4];
#pragma unroll
            for (int mt = 0; mt < 4; ++mt)
                af[mt] = *reinterpret_cast<const bf16x8*>(&At[cur][(wm + mt * 16 + l16) * LDSP + ks * 32 + quad * 8]);
#pragma unroll
            for (int nt = 0; nt < 4; ++nt)
                bf[nt] = *reinterpret_cast<const bf16x8*>(&Bl[cur][(wn + nt * 16 + l16) * LDSP + ks * 32 + quad * 8]);
#pragma unroll
            for (int mt = 0; mt < 4; ++mt)
#pragma unroll
                for (int nt = 0; nt < 4; ++nt)
                    acc[mt][nt] = __builtin_amdgcn_mfma_f32_16x16x32_bf16(af[mt], bf[nt], acc[mt][nt], 0, 0, 0);
        }
        if (pre) {
            uint4* sa = reinterpret_cast<uint4*>(&At[cur ^ 1][r * LDSP + c0]);
            uint4* sb = reinterpret_cast<uint4*>(&Bl[cur ^ 1][r * LDSP + c0]);
            sa[0] = a0; sa[1] = a1; sa[2] = a2; sa[3] = a3;
            sb[0] = b0; sb[1] = b1; sb[2] = b2; sb[3] = b3;
        }
        cur ^= 1;
    }

    const int which = (n0 + wn) / DIM;          // 0=q 1=k 2=v (wave-uniform)
    const int head = ((n0 + wn) % DIM) / HD;
    const int b = m0 / NSEQ;
    const int tokb = m0 % NSEQ + wm;
    if (which == 2) {
#pragma unroll
        for (int mt = 0; mt < 4; ++mt)
#pragma unroll
            for (int nt = 0; nt < 4; ++nt) {
                const int n = n0 + wn + nt * 16 + l16;
                const int d = nt * 16 + l16;
                const float bi = bias[n];
                const int tok0 = tokb + mt * 16 + quad * 4;
                half4 hv;
                hv.x = (_Float16)(acc[mt][nt][0] + bi);
                hv.y = (_Float16)(acc[mt][nt][1] + bi);
                hv.z = (_Float16)(acc[mt][nt][2] + bi);
                hv.w = (_Float16)(acc[mt][nt][3] + bi);
                *reinterpret_cast<half4*>(&vtb[((size_t)(b * HEADS + head) * HD + d) * NSEQ + tok0]) = hv;
            }
    } else {
        // fused RoPE: pairs (d, d+32) = (nt, nt+2); pi = l16
        short* dst = (which == 0) ? qb : kbuf;
        const float qs = (which == 0) ? QSCALE : 1.0f;
        float bi[4];
#pragma unroll
        for (int nt = 0; nt < 4; ++nt) bi[nt] = bias[n0 + wn + nt * 16 + l16];
        const float invp = __builtin_amdgcn_exp2f(-(float)l16 * LOG2_100_D16); // 100^(-l16/16)
#pragma unroll
        for (int mt = 0; mt < 4; ++mt) {
#pragma unroll
            for (int rg = 0; rg < 4; ++rg) {
                const int tok = tokb + mt * 16 + quad * 4 + rg;
                const int yy = tok / 48, xx = tok - yy * 48;
                const float ry = (2.0f * (yy + 0.5f) * (1.0f / 48.0f) - 1.0f) * invp; // revolutions
                const float rx = (2.0f * (xx + 0.5f) * (1.0f / 48.0f) - 1.0f) * invp;
                const float sy = __builtin_amdgcn_sinf(ry), cy = __builtin_amdgcn_cosf(ry);
                const float sx = __builtin_amdgcn_sinf(rx), cx = __builtin_amdgcn_cosf(rx);
                const float a0 = acc[mt][0][rg] + bi[0];
                const float a1 = acc[mt][1][rg] + bi[1];
                const float a2 = acc[mt][2][rg] + bi[2];
                const float a3 = acc[mt][3][rg] + bi[3];
                short* rp = &dst[((size_t)(b * HEADS + head) * NSEQ + tok) * HD];
                rp[l16]      = f2bf((a0 * cy - a2 * sy) * qs);
                rp[32 + l16] = f2bf((a2 * cy + a0 * sy) * qs);
                rp[16 + l16] = f2bf((a1 * cx - a3 * sx) * qs);
                rp[48 + l16] = f2bf((a3 * cx + a1 * sx) * qs);
            }
        }
    }
}

// ---------------- flash attention: 64 q-rows/wave, key-split, XCD-swizzled ----------------
// 432 blocks (9 q-tiles x 2 kh x 24 bh). Each wave: 64 q-rows; block: 256 rows.
// Per 64-key tile per wave: 32 K=32 QK MFMAs + 64 K=16 PV + 16 l-sum vs 24 ds_reads
// (2x MFMA per LDS read / per barrier vs 32-row version).
__global__ __launch_bounds__(256, 2) void attn_kernel(
    const short* __restrict__ qb, const short* __restrict__ kb,
    const _Float16* __restrict__ vtb, _Float16* __restrict__ opart,
    float* __restrict__ lpart)
{
    __shared__ __align__(16) short    Kt[2][64 * KP];   // [key][d]   bf16
    __shared__ __align__(16) _Float16 Vt[2][64 * KP];   // [d][tok]   f16
    const int wg = blockIdx.x;
    const int xcd = wg & 7;
    const int slot = wg >> 3;              // 0..53
    const int slab = xcd * 6 + slot / 9;   // 0..47 (all 9 q-tiles of a slab on one XCD)
    const int qt = slot % 9;
    const int kh = slab & 1;
    const int bh = slab >> 1;
    const int tid = threadIdx.x, lane = tid & 63, wave = tid >> 6;
    const int quad = lane >> 4, l16 = lane & 15;
    const int qrow0 = qt * 256 + wave * 64;
    const short* qbase = qb + (size_t)bh * NSEQ * HD;
    const short* kbase = kb + (size_t)bh * NSEQ * HD;
    const _Float16* vbase = vtb + (size_t)bh * HD * NSEQ;

    bf16x8 qf[4][2];
#pragma unroll
    for (int mt = 0; mt < 4; ++mt)
#pragma unroll
        for (int ks = 0; ks < 2; ++ks)
            qf[mt][ks] = *reinterpret_cast<const bf16x8*>(
                &qbase[(size_t)(qrow0 + mt * 16 + l16) * HD + ks * 32 + quad * 8]);

    half4 ones;
    ones.x = ones.y = ones.z = ones.w = (_Float16)1.0f;

    f32x4 oacc[4][4] = {};
    f32x4 lacc[4] = {};

    const int r = tid >> 2, cq = (tid & 3) * 16;
    const int t0 = kh * KT_HALF;
    const short* kp = kbase + (size_t)(t0 * 64 + r) * HD + cq;
    const _Float16* vp = vbase + (size_t)r * NSEQ + t0 * 64 + cq;
    // prologue: stage first tile into buffer 0
    {
        const uint4* gk = reinterpret_cast<const uint4*>(kp);
        uint4 k0 = gk[0], k1 = gk[1];
        const uint4* gv = reinterpret_cast<const uint4*>(vp);
        uint4 v0 = gv[0], v1 = gv[1];
        uint4* sk = reinterpret_cast<uint4*>(&Kt[0][r * KP + cq]);
        sk[0] = k0; sk[1] = k1;
        uint4* sv = reinterpret_cast<uint4*>(&Vt[0][r * KP + cq]);
        sv[0] = v0; sv[1] = v1;
        kp += 64 * HD;
        vp += 64;
    }

    int cur = 0;
    for (int kt = 0; kt < KT_HALF; ++kt) {
        __syncthreads();   // buf[cur] visible; readers of buf[cur^1] done
        uint4 k0, k1, v0, v1;
        const bool pre = (kt + 1 < KT_HALF);
        if (pre) {
            const uint4* gk = reinterpret_cast<const uint4*>(kp);
            k0 = gk[0]; k1 = gk[1];
            const uint4* gv = reinterpret_cast<const uint4*>(vp);
            v0 = gv[0]; v1 = gv[1];
            kp += 64 * HD;
            vp += 64;
        }

        // hoist K and V^T fragments once, reuse over 4 m-tiles
        bf16x8 kf[2][4];
#pragma unroll
        for (int ks = 0; ks < 2; ++ks)
#pragma unroll
            for (int nt = 0; nt < 4; ++nt)
                kf[ks][nt] = *reinterpret_cast<const bf16x8*>(
                    &Kt[cur][(nt * 16 + l16) * KP + ks * 32 + quad * 8]);
        half4 vf[4][4];
#pragma unroll
        for (int nt = 0; nt < 4; ++nt)
#pragma unroll
            for (int dt = 0; dt < 4; ++dt)
                vf[nt][dt] = *reinterpret_cast<const half4*>(
                    &Vt[cur][(dt * 16 + l16) * KP + nt * 16 + quad * 4]);

#pragma unroll
        for (int mt = 0; mt < 4; ++mt) {
            // S^T = K Q^T for this 16-row m-tile
            f32x4 sacc[4] = {};
#pragma unroll
            for (int ks = 0; ks < 2; ++ks)
#pragma unroll
                for (int nt = 0; nt < 4; ++nt)
                    sacc[nt] = __builtin_amdgcn_mfma_f32_16x16x32_bf16(
                        kf[ks][nt], qf[mt][ks], sacc[nt], 0, 0, 0);

            // P = exp2(S^T) -> f16 A-fragments in registers
            half4 pf[4];
#pragma unroll
            for (int nt = 0; nt < 4; ++nt) {
                fp16x2 lo = __builtin_amdgcn_cvt_pkrtz(
                    __builtin_amdgcn_exp2f(sacc[nt][0]),
                    __builtin_amdgcn_exp2f(sacc[nt][1]));
                fp16x2 hi = __builtin_amdgcn_cvt_pkrtz(
                    __builtin_amdgcn_exp2f(sacc[nt][2]),
                    __builtin_amdgcn_exp2f(sacc[nt][3]));
                half4 p;
                p.x = (_Float16)lo.x; p.y = (_Float16)lo.y;
                p.z = (_Float16)hi.x; p.w = (_Float16)hi.y;
                pf[nt] = p;
            }

            // l += P * ones ; O += P V
#pragma unroll
            for (int nt = 0; nt < 4; ++nt)
                lacc[mt] = __builtin_amdgcn_mfma_f32_16x16x16f16(
                    pf[nt], ones, lacc[mt], 0, 0, 0);
#pragma unroll
            for (int nt = 0; nt < 4; ++nt)
#pragma unroll
                for (int dt = 0; dt < 4; ++dt)
                    oacc[mt][dt] = __builtin_amdgcn_mfma_f32_16x16x16f16(
                        pf[nt], vf[nt][dt], oacc[mt][dt], 0, 0, 0);
        }

        if (pre) {   // stage next tile; vmcnt wait lands after the tile's compute
            uint4* sk = reinterpret_cast<uint4*>(&Kt[cur ^ 1][r * KP + cq]);
            sk[0] = k0; sk[1] = k1;
            uint4* sv = reinterpret_cast<uint4*>(&Vt[cur ^ 1][r * KP + cq]);
            sv[0] = v0; sv[1] = v1;
        }
        cur ^= 1;
    }

    // store UNNORMALIZED partials
    _Float16* ob2 = opart + (size_t)(kh * BH + bh) * NSEQ * HD;
    float* lp2 = lpart + (size_t)(kh * BH + bh) * NSEQ;
#pragma unroll
    for (int mt = 0; mt < 4; ++mt) {
#pragma unroll
        for (int dt = 0; dt < 4; ++dt)
#pragma unroll
            for (int rg = 0; rg < 4; ++rg) {
                int row = qrow0 + mt * 16 + quad * 4 + rg;
                ob2[(size_t)row * HD + dt * 16 + l16] = (_Float16)oacc[mt][dt][rg];
            }
        if (l16 == 0) {
#pragma unroll
            for (int rg = 0; rg < 4; ++rg)
                lp2[qrow0 + mt * 16 + quad * 4 + rg] = lacc[mt][rg];
        }
    }
}

// ---------------- proj GEMM with fused softmax-combine ----------------
__global__ __launch_bounds__(256) void gemm_proj_kernel(
    const _Float16* __restrict__ op,  // [2][bh][row][d] f16 partials
    const float* __restrict__ lp,     // [2][bh][row] f32 partials
    const short* __restrict__ Bt,     // wprojb [768,768]
    const float* __restrict__ bias,   // [768]
    float* __restrict__ out)
{
    __shared__ __align__(16) short At[64 * LDSP];
    __shared__ __align__(16) short Bl[64 * LDSP];
    const int m0 = blockIdx.x * 64, n0 = blockIdx.y * 64;
    const int tid = threadIdx.x, lane = tid & 63, wave = tid >> 6;
    const int quad = lane >> 4, l16 = lane & 15;
    const int wm = (wave >> 1) * 32, wn = (wave & 1) * 32;
    const int r = tid >> 2, cs = (tid & 3) * 16;
    const int b = m0 / NSEQ;
    const int tok = m0 % NSEQ + r;
    f32x4 acc[2][2] = {};

    for (int k0 = 0; k0 < DIM; k0 += 64) {
        // fused combine: this k-tile is head h
        const int h = k0 >> 6;
        const size_t pb = (size_t)(b * HEADS + h) * NSEQ + tok;
        const float l0 = lp[pb], l1 = lp[(size_t)BH * NSEQ + pb];
        const float inv = __builtin_amdgcn_rcpf(l0 + l1);
        const half8* o0 = reinterpret_cast<const half8*>(&op[pb * HD + cs]);
        const half8* o1 = reinterpret_cast<const half8*>(&op[(size_t)BH * NSEQ * HD + pb * HD + cs]);
        half8 p0 = o0[0], p1 = o0[1], q0 = o1[0], q1 = o1[1];
        const uint4* gb = reinterpret_cast<const uint4*>(&Bt[(size_t)(n0 + r) * DIM + k0 + cs]);
        uint4 bw0 = gb[0], bw1 = gb[1];
        short8v s0, s1;
#pragma unroll
        for (int j = 0; j < 8; ++j) {
            s0[j] = f2bf(((float)p0[j] + (float)q0[j]) * inv);
            s1[j] = f2bf(((float)p1[j] + (float)q1[j]) * inv);
        }
        *reinterpret_cast<short8v*>(&At[r * LDSP + cs]) = s0;
        *reinterpret_cast<short8v*>(&At[r * LDSP + cs + 8]) = s1;
        uint4* sb = reinterpret_cast<uint4*>(&Bl[r * LDSP + cs]);
        sb[0] = bw0; sb[1] = bw1;
        __syncthreads();
#pragma unroll
        for (int ks = 0; ks < 2; ++ks) {
            bf16x8 af[2], bf[2];
#pragma unroll
            for (int mt = 0; mt < 2; ++mt)
                af[mt] = *reinterpret_cast<const bf16x8*>(&At[(wm + mt * 16 + l16) * LDSP + ks * 32 + quad * 8]);
#pragma unroll
            for (int nt = 0; nt < 2; ++nt)
                bf[nt] = *reinterpret_cast<const bf16x8*>(&Bl[(wn + nt * 16 + l16) * LDSP + ks * 32 + quad * 8]);
#pragma unroll
            for (int mt = 0; mt < 2; ++mt)
#pragma unroll
                for (int nt = 0; nt < 2; ++nt)
                    acc[mt][nt] = __builtin_amdgcn_mfma_f32_16x16x32_bf16(af[mt], bf[nt], acc[mt][nt], 0, 0, 0);
        }
        __syncthreads();
    }

#pragma unroll
    for (int mt = 0; mt < 2; ++mt)
#pragma unroll
        for (int nt = 0; nt < 2; ++nt) {
            const int n = n0 + wn + nt * 16 + l16;
            const float bi = bias[n];
#pragma unroll
            for (int rg = 0; rg < 4; ++rg) {
                const int m = m0 + wm + mt * 16 + quad * 4 + rg;
                out[(size_t)m * DIM + n] = acc[mt][nt][rg] + bi;
            }
        }
}

extern "C" void kernel_launch(void* const* d_in, const int* in_sizes, int n_in,
                              void* d_out, int out_size, void* d_ws, size_t ws_size,
                              hipStream_t stream) {
    const float* x      = (const float*)d_in[0];
    const float* w_qkv  = (const float*)d_in[1];
    const float* b_qkv  = (const float*)d_in[2];
    const float* w_proj = (const float*)d_in[3];
    const float* b_proj = (const float*)d_in[4];
    float* out = (float*)d_out;

    short* xb     = (short*)d_ws;                         // 4608*768
    short* wqkvb  = xb + (size_t)M_TOK * DIM;             // 2304*768
    short* wprojb = wqkvb + (size_t)3 * DIM * DIM;        // 768*768
    short* qb     = wprojb + (size_t)DIM * DIM;           // 24*2304*64 bf16
    short* kb     = qb + (size_t)BH * NSEQ * HD;
    short* vtb    = kb + (size_t)BH * NSEQ * HD;          // f16 [bh,d,tok]
    short* opart  = vtb + (size_t)BH * NSEQ * HD;         // f16 [2,bh,row,d]
    float* lpart  = (float*)(opart + (size_t)2 * BH * NSEQ * HD); // f32 [2,bh,row]

    // merged converts (1 kernel)
    cvt_all_kernel<<<(CN1 + CN2 + CN3) / 256, 256, 0, stream>>>(
        x, w_qkv, w_proj, xb, wqkvb, wprojb);

    // qkv GEMM + bias + RoPE + QSCALE + scatter (double-buffered)
    dim3 g1(M_TOK / 128, 3 * DIM / 128);
    gemm_qkv_kernel<<<g1, 256, 0, stream>>>(xb, wqkvb, b_qkv, qb, kb, (_Float16*)vtb);

    // attention partials (key-split x2), 64 q-rows/wave, XCD-swizzled 1D grid
    attn_kernel<<<dim3(9 * 2 * BH), 256, 0, stream>>>(qb, kb, (const _Float16*)vtb,
                                                      (_Float16*)opart, lpart);

    // proj GEMM with fused combine+normalize
    dim3 g3(M_TOK / 64, DIM / 64);
    gemm_proj_kernel<<<g3, 256, 0, stream>>>((const _Float16*)opart, lpart,
                                             wprojb, b_proj, out);
}